// Round 8
// baseline (1076.844 us; speedup 1.0000x reference)
//
#include <hip/hip_runtime.h>
#include <hip/hip_bf16.h>
#include <stdint.h>

#define K_DIM 40960
#define NROWS 8192
#define ACCH 256
#define KSPLIT 4
#define KCHUNK (K_DIM / KSPLIT)   // 10240
#define BM 256
#define BK 64
#define NT (KCHUNK / BK)          // 160

typedef float f32x4 __attribute__((ext_vector_type(4)));
typedef _Float16 f16x8 __attribute__((ext_vector_type(8)));

// RNE f32 -> f16 pair pack (v_cvt_f16_f32 is RNE by default; RTZ would bias)
__device__ __forceinline__ uint32_t pack2_f16(float a, float b) {
  _Float16 ha = (_Float16)a, hb = (_Float16)b;
  uint16_t ua = __builtin_bit_cast(uint16_t, ha);
  uint16_t ub = __builtin_bit_cast(uint16_t, hb);
  return (uint32_t)ua | ((uint32_t)ub << 16);
}

__device__ __forceinline__ void gload_lds16(const void* g, void* l) {
  __builtin_amdgcn_global_load_lds((const __attribute__((address_space(1))) uint32_t*)g,
                                   (__attribute__((address_space(3))) uint32_t*)l, 16, 0, 0);
}

// ---------------- kernel 1: fp32 -> fp16 weight conversion (RNE) ----------------
__global__ void convert_w_kernel(const float* __restrict__ ww, const float* __restrict__ wb,
                                 uint16_t* __restrict__ dst) {
  uint32_t gid = blockIdx.x * blockDim.x + threadIdx.x;
  uint64_t e = (uint64_t)gid * 8u;
  const uint64_t half = (uint64_t)ACCH * K_DIM;
  const float* src = (e < half) ? (ww + e) : (wb + (e - half));
  float4 f0 = *(const float4*)src;
  float4 f1 = *(const float4*)(src + 4);
  uint4 o;
  o.x = pack2_f16(f0.x, f0.y);
  o.y = pack2_f16(f0.z, f0.w);
  o.z = pack2_f16(f1.x, f1.y);
  o.w = pack2_f16(f1.z, f1.w);
  *(uint4*)(dst + e) = o;
}

// ---------------- kernel 2: split-K feature-transformer GEMM (fp16 MFMA) ----------
// r8 = r7 schedule with the VGPR cap LIFTED: __launch_bounds__(512,1).
// r7's 1075us regression was a spill storm from the (512,2)-implied 128-VGPR cap
// (WRITE_SIZE 855MB of scratch); LDS already limits us to 1 block/CU, so the cap
// bought nothing. Deep-A schedule: av double-banked, loadA(t+3) issued one iter
// early -> writeA(t+1)'s counted wait has a full iteration of slack.
// End-of-iter barrier vmcnt(20): outstanding B(t+1)4+A(t+2)8+B(t+2)4+A(t+3)8=24,
// retire 4 oldest = B(t+1). Tail: vmcnt(12) at t==NT-3, vmcnt(0) after.
__global__ __launch_bounds__(512, 1) void ft_gemm(
    const float* __restrict__ featW, const float* __restrict__ featB,
    const uint16_t* __restrict__ wts, float* __restrict__ partials)
{
  extern __shared__ char smem[];
  const int tid = threadIdx.x;
  const int bid = blockIdx.x;
  // XCD-aware remap: (cc,ksp) = bid&7 so same B-panel stays on one XCD's L2
  const int mt  = bid >> 3;
  const int cc  = bid & 1;
  const int ksp = (bid >> 1) & 3;
  const float*    feat = cc ? featB : featW;
  const uint16_t* wp   = wts + (uint64_t)cc * ACCH * K_DIM;
  const int m0 = mt * BM;
  const int k0 = ksp * KCHUNK;

  const int wid  = tid >> 6;
  const int lane = tid & 63;
  const int wm   = wid >> 2;   // 0..1
  const int wn   = wid & 3;    // 0..3
  const int lrow = lane & 15;
  const int lk   = lane >> 4;  // 0..3

  // A staging: 4 segments of 8 floats per thread; segment p = base + p*64 rows
  const int ar0 = tid >> 3, as0 = tid & 7;
  const float* aSrc0 = feat + (uint64_t)(m0 + ar0) * K_DIM + k0 + as0 * 8;
  // swizzled LDS byte offset: slot as0 ^ (row&7), row pitch 128B
  const int aOff0 = ar0 * 128 + ((as0 ^ (ar0 & 7)) * 16);

  // B staging: 4 global_load_lds(16B) per thread; instr i = base + i*64 rows.
  // LDS dest linear; global source pre-swizzled: chunk = (l&7) ^ (row&7)
  const int gsegB = wid * 64 + lane;
  const int br0 = gsegB >> 3;
  const int bs0 = (gsegB & 7) ^ (br0 & 7);
  const uint16_t* bSrc0 = wp + (uint64_t)br0 * K_DIM + k0 + bs0 * 8;

  float4 av0[4][2], av1[4][2];   // two A register banks (tiles alternate banks)
  auto loadA = [&](float4 (&av)[4][2]) {
    #pragma unroll
    for (int p = 0; p < 4; ++p) {
      const float* s = aSrc0 + (uint64_t)p * 64u * K_DIM;
      av[p][0] = *(const float4*)(s);
      av[p][1] = *(const float4*)(s + 4);
    }
    aSrc0 += BK;
  };
  auto writeA = [&](int buf, const float4 (&av)[4][2]) {  // buf in {0,1}
    #pragma unroll
    for (int p = 0; p < 4; ++p) {
      uint4 o;
      o.x = pack2_f16(av[p][0].x, av[p][0].y);
      o.y = pack2_f16(av[p][0].z, av[p][0].w);
      o.z = pack2_f16(av[p][1].x, av[p][1].y);
      o.w = pack2_f16(av[p][1].z, av[p][1].w);
      *(uint4*)(smem + buf * 32768 + aOff0 + p * 8192) = o;
    }
  };
  auto issueB = [&](int buf) {   // buf in {0,1,2}, 32 KB each at offset 64K
    #pragma unroll
    for (int i = 0; i < 4; ++i) {
      gload_lds16(bSrc0 + (uint64_t)i * 64u * K_DIM,
                  smem + 65536 + buf * 32768 + (i * 8 + wid) * 1024);
    }
    bSrc0 += BK;
  };

  f32x4 acc[8][4];
  #pragma unroll
  for (int m = 0; m < 8; ++m)
    #pragma unroll
    for (int n = 0; n < 4; ++n)
      acc[m][n] = (f32x4){0.f, 0.f, 0.f, 0.f};

  auto mfma_step = [&](const char* Ab, const char* Bb) {
    #pragma unroll
    for (int ksub = 0; ksub < 2; ++ksub) {
      f16x8 af[8], bfr[4];
      #pragma unroll
      for (int m = 0; m < 8; ++m)
        af[m] = *(const f16x8*)(Ab + (wm * 128 + m * 16 + lrow) * 128
                                   + (((ksub * 4 + lk) ^ (lrow & 7)) * 16));
      #pragma unroll
      for (int n = 0; n < 4; ++n)
        bfr[n] = *(const f16x8*)(Bb + (wn * 64 + n * 16 + lrow) * 128
                                    + (((ksub * 4 + lk) ^ (lrow & 7)) * 16));
      #pragma unroll
      for (int m = 0; m < 8; ++m)
        #pragma unroll
        for (int n = 0; n < 4; ++n)
          acc[m][n] = __builtin_amdgcn_mfma_f32_16x16x32_f16(af[m], bfr[n], acc[m][n], 0, 0, 0);
    }
  };

  // prologue: A(0)->av0; B(0); stage A(0) [waits av0, leaves B0]; A(1)->av1;
  // B(1); A(2)->av0 [bank0 freed]. Barrier retires B(0): leaves A1+B1+A2 = 20.
  loadA(av0);
  issueB(0);
  writeA(0, av0);
  loadA(av1);
  issueB(1);
  loadA(av0);
  asm volatile("s_waitcnt vmcnt(20) lgkmcnt(0)" ::: "memory");
  __builtin_amdgcn_s_barrier();

  int bcur = 0;                    // t % 3 at even position
  for (int tt = 0; tt < NT; tt += 2) {
    // ---- even iter t = tt: A-LDS buf0, B buf bcur, av bank: write av1, load av1
    {
      const int t = tt;
      const int bn2 = (bcur >= 1) ? bcur - 1 : bcur + 2;   // (t+2) % 3
      if (t < NT - 2) issueB(bn2);
      asm volatile("" ::: "memory");
      if (t < NT - 1) writeA(1, av1);      // stage A(t+1); waits av1 (counted)
      asm volatile("" ::: "memory");
      if (t < NT - 3) loadA(av1);          // A(t+3) -> bank1 (just freed)
      asm volatile("" ::: "memory");
      mfma_step(smem, smem + 65536 + bcur * 32768);
      if (t < NT - 3) asm volatile("s_waitcnt vmcnt(20) lgkmcnt(0)" ::: "memory");
      else            asm volatile("s_waitcnt vmcnt(0) lgkmcnt(0)" ::: "memory");
      __builtin_amdgcn_s_barrier();
    }
    // ---- odd iter t = tt+1: A-LDS buf1, B buf (bcur+1)%3, write av0, load av0
    {
      const int t = tt + 1;
      const int b1 = (bcur >= 2) ? bcur - 2 : bcur + 1;    // (t) % 3
      if (t < NT - 2) issueB(bcur);        // (t+2)%3 == bcur (read finished at t-1)
      asm volatile("" ::: "memory");
      if (t < NT - 1) writeA(0, av0);      // stage A(t+1)
      asm volatile("" ::: "memory");
      if (t < NT - 3) loadA(av0);          // A(t+3) -> bank0
      asm volatile("" ::: "memory");
      mfma_step(smem + 32768, smem + 65536 + b1 * 32768);
      if (t < NT - 3)       asm volatile("s_waitcnt vmcnt(20) lgkmcnt(0)" ::: "memory");
      else if (t == NT - 3) asm volatile("s_waitcnt vmcnt(12) lgkmcnt(0)" ::: "memory");
      else                  asm volatile("s_waitcnt vmcnt(0) lgkmcnt(0)" ::: "memory");
      __builtin_amdgcn_s_barrier();
      bcur = (bcur >= 1) ? bcur - 1 : bcur + 2;            // += 2 mod 3
    }
  }

  // epilogue: write fp32 partials [color*KSPLIT+ksp][8192][256]
  float* pbase = partials + ((uint64_t)(cc * KSPLIT + ksp) * NROWS + m0) * ACCH;
  #pragma unroll
  for (int m = 0; m < 8; ++m) {
    #pragma unroll
    for (int n = 0; n < 4; ++n) {
      int row = wm * 128 + m * 16 + lk * 4;
      int col = wn * 64 + n * 16 + lrow;
      float* dst = pbase + (uint64_t)row * ACCH + col;
      dst[0]        = acc[m][n][0];
      dst[ACCH]     = acc[m][n][1];
      dst[2 * ACCH] = acc[m][n][2];
      dst[3 * ACCH] = acc[m][n][3];
    }
  }
}

// ---------------- kernel 3: reduce partials + stm-mix + clip + MLP tail (all fp32) ----
// 512 blocks x 128 threads; each block: 16 rows.
__global__ __launch_bounds__(128) void tail_kernel(
    const float* __restrict__ partials, const float* __restrict__ stm,
    const float* __restrict__ bw, const float* __restrict__ bb,
    const float* __restrict__ w1, const float* __restrict__ b1,
    const float* __restrict__ w2, const float* __restrict__ b2,
    const float* __restrict__ w_out, const float* __restrict__ b_out,
    float* __restrict__ out)
{
  __shared__ float in1[16 * 513];   // pitch 513: conflict-free cross-row reads
  __shared__ float out1c[16 * 33];
  const int t = threadIdx.x;
  const int b0 = blockIdx.x * 16;

  // phase 1: reduce split-K partials, stm-mix, clip -> in1[16][512]
  for (int it = 0; it < 32; ++it) {
    int item = t + it * 128;        // 0..4095
    int jc = item & 255;
    int rr = item >> 8;             // 0..15
    int b  = b0 + rr;
    float wsum = bw[jc], bsum = bb[jc];
    #pragma unroll
    for (int k = 0; k < KSPLIT; ++k) {
      wsum += partials[((uint64_t)(0 * KSPLIT + k) * NROWS + b) * ACCH + jc];
      bsum += partials[((uint64_t)(1 * KSPLIT + k) * NROWS + b) * ACCH + jc];
    }
    float s = stm[b];
    float lo = (1.f - s) * wsum + s * bsum;
    float hi = (1.f - s) * bsum + s * wsum;
    in1[rr * 513 + jc]       = fminf(fmaxf(lo, 0.f), 1.f);
    in1[rr * 513 + 256 + jc] = fminf(fmaxf(hi, 0.f), 1.f);
  }
  __syncthreads();

  // layer 1: 512 -> 32, thread (row rl, o-group og) computes o = og*4+oi
  const int rl = t >> 3, og = t & 7;
  float a1[4] = {0.f, 0.f, 0.f, 0.f};
  for (int j = 0; j < 512; j += 4) {
    float v0 = in1[rl * 513 + j];
    float v1 = in1[rl * 513 + j + 1];
    float v2 = in1[rl * 513 + j + 2];
    float v3 = in1[rl * 513 + j + 3];
    #pragma unroll
    for (int oi = 0; oi < 4; ++oi) {
      const float4 wv = *(const float4*)(w1 + (og * 4 + oi) * 512 + j);
      a1[oi] += v0 * wv.x + v1 * wv.y + v2 * wv.z + v3 * wv.w;
    }
  }
  #pragma unroll
  for (int oi = 0; oi < 4; ++oi) {
    int o = og * 4 + oi;
    out1c[rl * 33 + o] = fminf(fmaxf(a1[oi] + b1[o], 0.f), 1.f);
  }
  __syncthreads();

  // layer 2: 32 -> 32
  float a2[4] = {0.f, 0.f, 0.f, 0.f};
  for (int j = 0; j < 32; ++j) {
    float v = out1c[rl * 33 + j];
    #pragma unroll
    for (int oi = 0; oi < 4; ++oi) a2[oi] += v * w2[(og * 4 + oi) * 32 + j];
  }
  // layer 3: 32 -> 1 (clip then dot w_out), reduce across the 8 og lanes
  float p = 0.f;
  #pragma unroll
  for (int oi = 0; oi < 4; ++oi) {
    int o = og * 4 + oi;
    p += fminf(fmaxf(a2[oi] + b2[o], 0.f), 1.f) * w_out[o];
  }
  p += __shfl_xor(p, 1, 64);
  p += __shfl_xor(p, 2, 64);
  p += __shfl_xor(p, 4, 64);
  if (og == 0) out[b0 + rl] = p + b_out[0];
}

extern "C" void kernel_launch(void* const* d_in, const int* in_sizes, int n_in,
                              void* d_out, int out_size, void* d_ws, size_t ws_size,
                              hipStream_t stream) {
  (void)in_sizes; (void)n_in; (void)out_size; (void)ws_size;
  const float* wfeat   = (const float*)d_in[0];
  const float* bfeat   = (const float*)d_in[1];
  const float* stm     = (const float*)d_in[2];
  const float* w_white = (const float*)d_in[3];
  const float* b_white = (const float*)d_in[4];
  const float* w_black = (const float*)d_in[5];
  const float* b_black = (const float*)d_in[6];
  const float* w1      = (const float*)d_in[7];
  const float* b1      = (const float*)d_in[8];
  const float* w2      = (const float*)d_in[9];
  const float* b2      = (const float*)d_in[10];
  const float* w_out   = (const float*)d_in[11];
  const float* b_out   = (const float*)d_in[12];
  float* out = (float*)d_out;

  uint16_t* wf16     = (uint16_t*)d_ws;                                   // 41,943,040 B
  float*    partials = (float*)((char*)d_ws + (uint64_t)2 * ACCH * K_DIM * 2); // 67,108,864 B

  // kernel 1: weights fp32 -> fp16 (2*256*40960 / 8 per thread = 2,621,440 threads)
  convert_w_kernel<<<10240, 256, 0, stream>>>(w_white, w_black, wf16);

  // kernel 2: main GEMM, 160 KiB dynamic LDS (2x32K A-dbuf + 3x32K B-tribuf)
  (void)hipFuncSetAttribute((const void*)ft_gemm,
                            hipFuncAttributeMaxDynamicSharedMemorySize, 163840);
  ft_gemm<<<256, 512, 163840, stream>>>(wfeat, bfeat, wf16, partials);

  // kernel 3: fused reduce + mix + clip + MLP
  tail_kernel<<<512, 128, 0, stream>>>(partials, stm, b_white, b_black,
                                       w1, b1, w2, b2, w_out, b_out, out);
}

// Round 9
// 726.352 us; speedup vs baseline: 1.4825x; 1.4825x over previous
//
#include <hip/hip_runtime.h>
#include <hip/hip_bf16.h>
#include <stdint.h>

#define K_DIM 40960
#define NROWS 8192
#define ACCH 256
#define KSPLIT 2
#define KCHUNK (K_DIM / KSPLIT)   // 20480
#define BM 128
#define BK 64
#define NT (KCHUNK / BK)          // 320

typedef float f32x4 __attribute__((ext_vector_type(4)));
typedef _Float16 f16x8 __attribute__((ext_vector_type(8)));

// RNE f32 -> f16 pair pack (v_cvt_f16_f32 is RNE by default; RTZ would bias)
__device__ __forceinline__ uint32_t pack2_f16(float a, float b) {
  _Float16 ha = (_Float16)a, hb = (_Float16)b;
  uint16_t ua = __builtin_bit_cast(uint16_t, ha);
  uint16_t ub = __builtin_bit_cast(uint16_t, hb);
  return (uint32_t)ua | ((uint32_t)ub << 16);
}

__device__ __forceinline__ void gload_lds16(const void* g, void* l) {
  __builtin_amdgcn_global_load_lds((const __attribute__((address_space(1))) uint32_t*)g,
                                   (__attribute__((address_space(3))) uint32_t*)l, 16, 0, 0);
}

// ---------------- kernel 1: fp32 -> fp16 weight conversion (RNE) ----------------
__global__ void convert_w_kernel(const float* __restrict__ ww, const float* __restrict__ wb,
                                 uint16_t* __restrict__ dst) {
  uint32_t gid = blockIdx.x * blockDim.x + threadIdx.x;
  uint64_t e = (uint64_t)gid * 8u;
  const uint64_t half = (uint64_t)ACCH * K_DIM;
  const float* src = (e < half) ? (ww + e) : (wb + (e - half));
  float4 f0 = *(const float4*)src;
  float4 f1 = *(const float4*)(src + 4);
  uint4 o;
  o.x = pack2_f16(f0.x, f0.y);
  o.y = pack2_f16(f0.z, f0.w);
  o.z = pack2_f16(f1.x, f1.y);
  o.w = pack2_f16(f1.z, f1.w);
  *(uint4*)(dst + e) = o;
}

// ---------------- kernel 2: split-K feature-transformer GEMM (fp16 MFMA) ----------
// r9 RETILE: BM=128, BN=256, KSPLIT=2 -> acc 4x4 frags = 64 AGPR (was 128).
// r7/r8 lesson: 512-thr block (8 waves) forces 2 waves/SIMD -> hard 256 unified
// regs/wave; 128-AGPR acc left no room for deep-A (spill storm). With 64 AGPR,
// deep-A fits: av double-banked (16 VGPR each), loadA(t+3) issued 1 iter early,
// writeA(t+1) waits loads issued 2 iters ago. B triple-buffered.
// LDS 128K: A dbuf 2x16K @0, B tribuf 3x32K @32K.
// vmcnt: steady barrier 12 (retire B(t+1); leaves A(t+2)4+B(t+2)4+A(t+3)4);
// t==NT-3 -> 8; last two iters -> 0. Prologue barrier 12.
__global__ __launch_bounds__(512, 2) void ft_gemm(
    const float* __restrict__ featW, const float* __restrict__ featB,
    const uint16_t* __restrict__ wts, float* __restrict__ partials)
{
  extern __shared__ char smem[];
  const int tid = threadIdx.x;
  const int bid = blockIdx.x;
  // XCD-aware remap: (cc,ksp) = bid&3, XCD = bid&7 -> each XCD serves one B-panel
  const int mt  = bid >> 2;          // 0..63
  const int cc  = bid & 1;
  const int ksp = (bid >> 1) & 1;
  const float*    feat = cc ? featB : featW;
  const uint16_t* wp   = wts + (uint64_t)cc * ACCH * K_DIM;
  const int m0 = mt * BM;
  const int k0 = ksp * KCHUNK;

  const int wid  = tid >> 6;
  const int lane = tid & 63;
  const int wm   = wid >> 2;   // 0..1 (64 rows each)
  const int wn   = wid & 3;    // 0..3 (64 cols each)
  const int lrow = lane & 15;
  const int lk   = lane >> 4;  // 0..3

  // A staging: thread t handles row t>>2, 16 contiguous floats at col (t&3)*16
  const int arow = tid >> 2, acq = tid & 3;
  const float* aSrc0 = feat + (uint64_t)(m0 + arow) * K_DIM + k0 + acq * 16;
  // two swizzled 16B slots: s = acq*2 + {0,1}; slot ^= row&7; row pitch 128B
  const int aOffA = arow * 128 + (((acq * 2)     ^ (arow & 7)) * 16);
  const int aOffB = arow * 128 + (((acq * 2 + 1) ^ (arow & 7)) * 16);

  // B staging: 4 gload_lds16 per thread; instr i = row br0 + i*64.
  // LDS dest linear; global source pre-swizzled: chunk = (l&7) ^ (row&7)
  const int gsegB = wid * 64 + lane;
  const int br0 = gsegB >> 3;        // 0..63
  const int bs0 = (gsegB & 7) ^ (br0 & 7);
  const uint16_t* bSrc0 = wp + (uint64_t)br0 * K_DIM + k0 + bs0 * 8;

  float4 av0[4], av1[4];             // two A register banks, 16 VGPR each
  auto loadA = [&](float4 (&av)[4]) {
    av[0] = *(const float4*)(aSrc0);
    av[1] = *(const float4*)(aSrc0 + 4);
    av[2] = *(const float4*)(aSrc0 + 8);
    av[3] = *(const float4*)(aSrc0 + 12);
    aSrc0 += BK;
  };
  auto writeA = [&](int buf, const float4 (&av)[4]) {  // buf {0,1}, 16KB each
    uint4 oA, oB;
    oA.x = pack2_f16(av[0].x, av[0].y); oA.y = pack2_f16(av[0].z, av[0].w);
    oA.z = pack2_f16(av[1].x, av[1].y); oA.w = pack2_f16(av[1].z, av[1].w);
    oB.x = pack2_f16(av[2].x, av[2].y); oB.y = pack2_f16(av[2].z, av[2].w);
    oB.z = pack2_f16(av[3].x, av[3].y); oB.w = pack2_f16(av[3].z, av[3].w);
    *(uint4*)(smem + buf * 16384 + aOffA) = oA;
    *(uint4*)(smem + buf * 16384 + aOffB) = oB;
  };
  auto issueB = [&](int buf) {       // buf {0,1,2}, 32KB each at offset 32K
    #pragma unroll
    for (int i = 0; i < 4; ++i) {
      gload_lds16(bSrc0 + (uint64_t)i * 64u * K_DIM,
                  smem + 32768 + buf * 32768 + (i * 8 + wid) * 1024);
    }
    bSrc0 += BK;
  };

  f32x4 acc[4][4];
  #pragma unroll
  for (int m = 0; m < 4; ++m)
    #pragma unroll
    for (int n = 0; n < 4; ++n)
      acc[m][n] = (f32x4){0.f, 0.f, 0.f, 0.f};

  auto mfma_step = [&](const char* Ab, const char* Bb) {
    #pragma unroll
    for (int ksub = 0; ksub < 2; ++ksub) {
      f16x8 af[4], bfr[4];
      #pragma unroll
      for (int m = 0; m < 4; ++m)
        af[m] = *(const f16x8*)(Ab + (wm * 64 + m * 16 + lrow) * 128
                                   + (((ksub * 4 + lk) ^ (lrow & 7)) * 16));
      #pragma unroll
      for (int n = 0; n < 4; ++n)
        bfr[n] = *(const f16x8*)(Bb + (wn * 64 + n * 16 + lrow) * 128
                                    + (((ksub * 4 + lk) ^ (lrow & 7)) * 16));
      #pragma unroll
      for (int m = 0; m < 4; ++m)
        #pragma unroll
        for (int n = 0; n < 4; ++n)
          acc[m][n] = __builtin_amdgcn_mfma_f32_16x16x32_f16(af[m], bfr[n], acc[m][n], 0, 0, 0);
    }
  };

  // prologue: A(0)->av0; B(0); writeA(0) [waits A(0)]; A(1)->av1; B(1); A(2)->av0.
  // Barrier retires B(0): outstanding A(1)4+B(1)4+A(2)4 = 12.
  loadA(av0);
  issueB(0);
  writeA(0, av0);
  loadA(av1);
  issueB(1);
  loadA(av0);
  asm volatile("s_waitcnt vmcnt(12) lgkmcnt(0)" ::: "memory");
  __builtin_amdgcn_s_barrier();

  int bcur = 0;                    // t % 3 at even position
  for (int tt = 0; tt < NT; tt += 2) {
    // ---- even iter t: A-LDS buf0, B buf bcur; write av1=A(t+1), load av1<-A(t+3)
    {
      const int t = tt;
      const int bn2 = (bcur >= 1) ? bcur - 1 : bcur + 2;   // (t+2) % 3
      if (t < NT - 2) issueB(bn2);
      asm volatile("" ::: "memory");
      if (t < NT - 1) writeA(1, av1);      // waits A(t+1), issued 2 iters ago
      asm volatile("" ::: "memory");
      if (t < NT - 3) loadA(av1);          // A(t+3) -> bank1 (just freed)
      asm volatile("" ::: "memory");
      mfma_step(smem, smem + 32768 + bcur * 32768);
      if (t < NT - 3) asm volatile("s_waitcnt vmcnt(12) lgkmcnt(0)" ::: "memory");
      else            asm volatile("s_waitcnt vmcnt(0) lgkmcnt(0)" ::: "memory");
      __builtin_amdgcn_s_barrier();
    }
    // ---- odd iter t: A-LDS buf1, B buf (bcur+1)%3; write av0, load av0
    {
      const int t = tt + 1;
      const int b1 = (bcur >= 2) ? bcur - 2 : bcur + 1;    // t % 3
      if (t < NT - 2) issueB(bcur);        // (t+2)%3 == bcur
      asm volatile("" ::: "memory");
      if (t < NT - 1) writeA(0, av0);
      asm volatile("" ::: "memory");
      if (t < NT - 3) loadA(av0);
      asm volatile("" ::: "memory");
      mfma_step(smem + 16384, smem + 32768 + b1 * 32768);
      if (t < NT - 3)       asm volatile("s_waitcnt vmcnt(12) lgkmcnt(0)" ::: "memory");
      else if (t == NT - 3) asm volatile("s_waitcnt vmcnt(8) lgkmcnt(0)" ::: "memory");
      else                  asm volatile("s_waitcnt vmcnt(0) lgkmcnt(0)" ::: "memory");
      __builtin_amdgcn_s_barrier();
      bcur = (bcur >= 1) ? bcur - 1 : bcur + 2;            // += 2 mod 3
    }
  }

  // epilogue: write fp32 partials [cc*KSPLIT+ksp][8192][256]
  float* pbase = partials + ((uint64_t)(cc * KSPLIT + ksp) * NROWS + m0) * ACCH;
  #pragma unroll
  for (int m = 0; m < 4; ++m) {
    #pragma unroll
    for (int n = 0; n < 4; ++n) {
      int row = wm * 64 + m * 16 + lk * 4;
      int col = wn * 64 + n * 16 + lrow;
      float* dst = pbase + (uint64_t)row * ACCH + col;
      dst[0]        = acc[m][n][0];
      dst[ACCH]     = acc[m][n][1];
      dst[2 * ACCH] = acc[m][n][2];
      dst[3 * ACCH] = acc[m][n][3];
    }
  }
}

// ---------------- kernel 3: reduce partials + stm-mix + clip + MLP tail (all fp32) ----
// 512 blocks x 128 threads; each block: 16 rows.
__global__ __launch_bounds__(128) void tail_kernel(
    const float* __restrict__ partials, const float* __restrict__ stm,
    const float* __restrict__ bw, const float* __restrict__ bb,
    const float* __restrict__ w1, const float* __restrict__ b1,
    const float* __restrict__ w2, const float* __restrict__ b2,
    const float* __restrict__ w_out, const float* __restrict__ b_out,
    float* __restrict__ out)
{
  __shared__ float in1[16 * 513];   // pitch 513: conflict-free cross-row reads
  __shared__ float out1c[16 * 33];
  const int t = threadIdx.x;
  const int b0 = blockIdx.x * 16;

  // phase 1: reduce split-K partials, stm-mix, clip -> in1[16][512]
  for (int it = 0; it < 32; ++it) {
    int item = t + it * 128;        // 0..4095
    int jc = item & 255;
    int rr = item >> 8;             // 0..15
    int b  = b0 + rr;
    float wsum = bw[jc], bsum = bb[jc];
    #pragma unroll
    for (int k = 0; k < KSPLIT; ++k) {
      wsum += partials[((uint64_t)(0 * KSPLIT + k) * NROWS + b) * ACCH + jc];
      bsum += partials[((uint64_t)(1 * KSPLIT + k) * NROWS + b) * ACCH + jc];
    }
    float s = stm[b];
    float lo = (1.f - s) * wsum + s * bsum;
    float hi = (1.f - s) * bsum + s * wsum;
    in1[rr * 513 + jc]       = fminf(fmaxf(lo, 0.f), 1.f);
    in1[rr * 513 + 256 + jc] = fminf(fmaxf(hi, 0.f), 1.f);
  }
  __syncthreads();

  // layer 1: 512 -> 32, thread (row rl, o-group og) computes o = og*4+oi
  const int rl = t >> 3, og = t & 7;
  float a1[4] = {0.f, 0.f, 0.f, 0.f};
  for (int j = 0; j < 512; j += 4) {
    float v0 = in1[rl * 513 + j];
    float v1 = in1[rl * 513 + j + 1];
    float v2 = in1[rl * 513 + j + 2];
    float v3 = in1[rl * 513 + j + 3];
    #pragma unroll
    for (int oi = 0; oi < 4; ++oi) {
      const float4 wv = *(const float4*)(w1 + (og * 4 + oi) * 512 + j);
      a1[oi] += v0 * wv.x + v1 * wv.y + v2 * wv.z + v3 * wv.w;
    }
  }
  #pragma unroll
  for (int oi = 0; oi < 4; ++oi) {
    int o = og * 4 + oi;
    out1c[rl * 33 + o] = fminf(fmaxf(a1[oi] + b1[o], 0.f), 1.f);
  }
  __syncthreads();

  // layer 2: 32 -> 32
  float a2[4] = {0.f, 0.f, 0.f, 0.f};
  for (int j = 0; j < 32; ++j) {
    float v = out1c[rl * 33 + j];
    #pragma unroll
    for (int oi = 0; oi < 4; ++oi) a2[oi] += v * w2[(og * 4 + oi) * 32 + j];
  }
  // layer 3: 32 -> 1 (clip then dot w_out), reduce across the 8 og lanes
  float p = 0.f;
  #pragma unroll
  for (int oi = 0; oi < 4; ++oi) {
    int o = og * 4 + oi;
    p += fminf(fmaxf(a2[oi] + b2[o], 0.f), 1.f) * w_out[o];
  }
  p += __shfl_xor(p, 1, 64);
  p += __shfl_xor(p, 2, 64);
  p += __shfl_xor(p, 4, 64);
  if (og == 0) out[b0 + rl] = p + b_out[0];
}

extern "C" void kernel_launch(void* const* d_in, const int* in_sizes, int n_in,
                              void* d_out, int out_size, void* d_ws, size_t ws_size,
                              hipStream_t stream) {
  (void)in_sizes; (void)n_in; (void)out_size; (void)ws_size;
  const float* wfeat   = (const float*)d_in[0];
  const float* bfeat   = (const float*)d_in[1];
  const float* stm     = (const float*)d_in[2];
  const float* w_white = (const float*)d_in[3];
  const float* b_white = (const float*)d_in[4];
  const float* w_black = (const float*)d_in[5];
  const float* b_black = (const float*)d_in[6];
  const float* w1      = (const float*)d_in[7];
  const float* b1      = (const float*)d_in[8];
  const float* w2      = (const float*)d_in[9];
  const float* b2      = (const float*)d_in[10];
  const float* w_out   = (const float*)d_in[11];
  const float* b_out   = (const float*)d_in[12];
  float* out = (float*)d_out;

  uint16_t* wf16     = (uint16_t*)d_ws;                                   // 41,943,040 B
  float*    partials = (float*)((char*)d_ws + (uint64_t)2 * ACCH * K_DIM * 2); // 33,554,432 B

  // kernel 1: weights fp32 -> fp16 (2*256*40960 / 8 per thread = 2,621,440 threads)
  convert_w_kernel<<<10240, 256, 0, stream>>>(w_white, w_black, wf16);

  // kernel 2: main GEMM, 128 KiB dynamic LDS (2x16K A-dbuf + 3x32K B-tribuf)
  (void)hipFuncSetAttribute((const void*)ft_gemm,
                            hipFuncAttributeMaxDynamicSharedMemorySize, 131072);
  ft_gemm<<<256, 512, 131072, stream>>>(wfeat, bfeat, wf16, partials);

  // kernel 3: fused reduce + mix + clip + MLP
  tail_kernel<<<512, 128, 0, stream>>>(partials, stm, b_white, b_black,
                                       w1, b1, w2, b2, w_out, b_out, out);
}

// Round 10
// 608.550 us; speedup vs baseline: 1.7695x; 1.1936x over previous
//
#include <hip/hip_runtime.h>
#include <hip/hip_bf16.h>
#include <stdint.h>

#define K_DIM 40960
#define NROWS 8192
#define ACCH 256
#define KSPLIT 4
#define KCHUNK (K_DIM / KSPLIT)   // 10240
#define BM 256
#define BK 64
#define NT (KCHUNK / BK)          // 160

typedef float f32x4 __attribute__((ext_vector_type(4)));
typedef _Float16 f16x8 __attribute__((ext_vector_type(8)));

// RNE f32 -> f16 pair pack (v_cvt_f16_f32 is RNE by default; RTZ would bias)
__device__ __forceinline__ uint32_t pack2_f16(float a, float b) {
  _Float16 ha = (_Float16)a, hb = (_Float16)b;
  uint16_t ua = __builtin_bit_cast(uint16_t, ha);
  uint16_t ub = __builtin_bit_cast(uint16_t, hb);
  return (uint32_t)ua | ((uint32_t)ub << 16);
}

__device__ __forceinline__ void gload_lds16(const void* g, void* l) {
  __builtin_amdgcn_global_load_lds((const __attribute__((address_space(1))) uint32_t*)g,
                                   (__attribute__((address_space(3))) uint32_t*)l, 16, 0, 0);
}

// ---------------- kernel 1: fp32 -> fp16 weight conversion (RNE) ----------------
__global__ void convert_w_kernel(const float* __restrict__ ww, const float* __restrict__ wb,
                                 uint16_t* __restrict__ dst) {
  uint32_t gid = blockIdx.x * blockDim.x + threadIdx.x;
  uint64_t e = (uint64_t)gid * 8u;
  const uint64_t half = (uint64_t)ACCH * K_DIM;
  const float* src = (e < half) ? (ww + e) : (wb + (e - half));
  float4 f0 = *(const float4*)src;
  float4 f1 = *(const float4*)(src + 4);
  uint4 o;
  o.x = pack2_f16(f0.x, f0.y);
  o.y = pack2_f16(f0.z, f0.w);
  o.z = pack2_f16(f1.x, f1.y);
  o.w = pack2_f16(f1.z, f1.w);
  *(uint4*)(dst + e) = o;
}

// ---------------- kernel 2: split-K feature-transformer GEMM (fp16 MFMA) ----------
// BEST-KNOWN CONFIG (r6, 609 us): grid 256 blocks, 512 thr (8 waves, 2x4),
// tile 256x256xBK64. LDS 160K: A dbuf 2x32K @0, B tribuf 3x32K @64K.
// T2 XOR-swizzle on A (swizzled ds_write) and B (pre-swizzled global source).
// Schedule per iter t: issueB(t+2) -> writeA(t+1) [compiler's counted vmcnt
// waits A(t+1) only; in-order retirement has already retired B(t+1)] ->
// loadA(t+2) -> MFMA -> lgkmcnt(0)-only barrier (loads stream across it).
// Design-space notes (r7-r9): 512thr forces 2 waves/SIMD -> 256 unified
// regs/wave; acc=128 AGPR caps av at ~32 VGPR -> deep-A impossible here, and
// smaller-acc tiles (BM=128) raise bytes/FLOP 33% (B re-reads) -> net loss.
// This config sustains ~7.3 TB/s combined (HBM A + LLC B) per-CU traffic,
// above the chip's measured 6.4-6.6 TB/s copy ceiling -> memory-roofline.
__global__ __launch_bounds__(512, 2) void ft_gemm(
    const float* __restrict__ featW, const float* __restrict__ featB,
    const uint16_t* __restrict__ wts, float* __restrict__ partials)
{
  extern __shared__ char smem[];
  const int tid = threadIdx.x;
  const int bid = blockIdx.x;
  // XCD-aware remap: (cc,ksp) = bid&7 so same B-panel stays on one XCD's L2
  const int mt  = bid >> 3;
  const int cc  = bid & 1;
  const int ksp = (bid >> 1) & 3;
  const float*    feat = cc ? featB : featW;
  const uint16_t* wp   = wts + (uint64_t)cc * ACCH * K_DIM;
  const int m0 = mt * BM;
  const int k0 = ksp * KCHUNK;

  const int wid  = tid >> 6;
  const int lane = tid & 63;
  const int wm   = wid >> 2;   // 0..1
  const int wn   = wid & 3;    // 0..3
  const int lrow = lane & 15;
  const int lk   = lane >> 4;  // 0..3

  // A staging: 4 segments of 8 floats per thread; segment p = base + p*64 rows
  const int ar0 = tid >> 3, as0 = tid & 7;
  const float* aSrc0 = feat + (uint64_t)(m0 + ar0) * K_DIM + k0 + as0 * 8;
  // swizzled LDS byte offset: slot as0 ^ (row&7), row pitch 128B
  const int aOff0 = ar0 * 128 + ((as0 ^ (ar0 & 7)) * 16);

  // B staging: 4 global_load_lds(16B) per thread; instr i = base + i*64 rows.
  // LDS dest linear; global source pre-swizzled: chunk = (l&7) ^ (row&7)
  const int gsegB = wid * 64 + lane;
  const int br0 = gsegB >> 3;
  const int bs0 = (gsegB & 7) ^ (br0 & 7);
  const uint16_t* bSrc0 = wp + (uint64_t)br0 * K_DIM + k0 + bs0 * 8;

  float4 av[4][2];
  auto loadA = [&]() {
    #pragma unroll
    for (int p = 0; p < 4; ++p) {
      const float* s = aSrc0 + (uint64_t)p * 64u * K_DIM;
      av[p][0] = *(const float4*)(s);
      av[p][1] = *(const float4*)(s + 4);
    }
    aSrc0 += BK;
  };
  auto writeA = [&](int buf) {   // buf in {0,1}, 32 KB each at offset 0
    #pragma unroll
    for (int p = 0; p < 4; ++p) {
      uint4 o;
      o.x = pack2_f16(av[p][0].x, av[p][0].y);
      o.y = pack2_f16(av[p][0].z, av[p][0].w);
      o.z = pack2_f16(av[p][1].x, av[p][1].y);
      o.w = pack2_f16(av[p][1].z, av[p][1].w);
      *(uint4*)(smem + buf * 32768 + aOff0 + p * 8192) = o;
    }
  };
  auto issueB = [&](int buf) {   // buf in {0,1,2}, 32 KB each at offset 64K
    #pragma unroll
    for (int i = 0; i < 4; ++i) {
      gload_lds16(bSrc0 + (uint64_t)i * 64u * K_DIM,
                  smem + 65536 + buf * 32768 + (i * 8 + wid) * 1024);
    }
    bSrc0 += BK;
  };

  // prologue: A(0); B(0); cvt A(0)->Ab0 [vmcnt(4) leaves B0]; A(1); B(1);
  // wait B(0) done (vmcnt(12): leaves A1+B1) + A ds_writes visible.
  loadA();
  issueB(0);
  writeA(0);
  loadA();
  issueB(1);
  asm volatile("s_waitcnt vmcnt(12) lgkmcnt(0)" ::: "memory");
  __builtin_amdgcn_s_barrier();

  f32x4 acc[8][4];
  #pragma unroll
  for (int m = 0; m < 8; ++m)
    #pragma unroll
    for (int n = 0; n < 4; ++n)
      acc[m][n] = (f32x4){0.f, 0.f, 0.f, 0.f};

  int bcur = 0;                    // t % 3
  for (int t = 0; t < NT; ++t) {
    const int acur = t & 1;
    const int bnx2 = (bcur >= 1) ? bcur - 1 : bcur + 2;   // (t+2) % 3
    // VMEM issue order pinned: B(t+2) first, then (after writeA) A(t+2).
    if (t < NT - 2) issueB(bnx2);
    asm volatile("" ::: "memory");
    if (t < NT - 1) writeA(acur ^ 1);  // consumes av=A(t+1); compiler waits vmcnt(4)
    asm volatile("" ::: "memory");
    if (t < NT - 2) loadA();           // av = A(t+2), stays in flight past barrier
    asm volatile("" ::: "memory");

    const char* Ab = smem + acur * 32768;
    const char* Bb = smem + 65536 + bcur * 32768;
    #pragma unroll
    for (int ksub = 0; ksub < 2; ++ksub) {
      f16x8 af[8], bfr[4];
      #pragma unroll
      for (int m = 0; m < 8; ++m)
        af[m] = *(const f16x8*)(Ab + (wm * 128 + m * 16 + lrow) * 128
                                   + (((ksub * 4 + lk) ^ (lrow & 7)) * 16));
      #pragma unroll
      for (int n = 0; n < 4; ++n)
        bfr[n] = *(const f16x8*)(Bb + (wn * 64 + n * 16 + lrow) * 128
                                    + (((ksub * 4 + lk) ^ (lrow & 7)) * 16));
      #pragma unroll
      for (int m = 0; m < 8; ++m)
        #pragma unroll
        for (int n = 0; n < 4; ++n)
          acc[m][n] = __builtin_amdgcn_mfma_f32_16x16x32_f16(af[m], bfr[n], acc[m][n], 0, 0, 0);
    }

    // barrier with NO vmcnt: B(t+1) already retired by writeA's in-order wait;
    // lgkmcnt(0) makes this iter's A ds_writes visible to all waves.
    asm volatile("s_waitcnt lgkmcnt(0)" ::: "memory");
    __builtin_amdgcn_s_barrier();
    bcur = (bcur >= 2) ? 0 : bcur + 1;
  }

  // epilogue: write fp32 partials [color*KSPLIT+ksp][8192][256]
  float* pbase = partials + ((uint64_t)(cc * KSPLIT + ksp) * NROWS + m0) * ACCH;
  #pragma unroll
  for (int m = 0; m < 8; ++m) {
    #pragma unroll
    for (int n = 0; n < 4; ++n) {
      int row = wm * 128 + m * 16 + lk * 4;
      int col = wn * 64 + n * 16 + lrow;
      float* dst = pbase + (uint64_t)row * ACCH + col;
      dst[0]        = acc[m][n][0];
      dst[ACCH]     = acc[m][n][1];
      dst[2 * ACCH] = acc[m][n][2];
      dst[3 * ACCH] = acc[m][n][3];
    }
  }
}

// ---------------- kernel 3: reduce partials + stm-mix + clip + MLP tail (all fp32) ----
// 512 blocks x 128 threads; each block: 16 rows.
__global__ __launch_bounds__(128) void tail_kernel(
    const float* __restrict__ partials, const float* __restrict__ stm,
    const float* __restrict__ bw, const float* __restrict__ bb,
    const float* __restrict__ w1, const float* __restrict__ b1,
    const float* __restrict__ w2, const float* __restrict__ b2,
    const float* __restrict__ w_out, const float* __restrict__ b_out,
    float* __restrict__ out)
{
  __shared__ float in1[16 * 513];   // pitch 513: conflict-free cross-row reads
  __shared__ float out1c[16 * 33];
  const int t = threadIdx.x;
  const int b0 = blockIdx.x * 16;

  // phase 1: reduce split-K partials, stm-mix, clip -> in1[16][512]
  for (int it = 0; it < 32; ++it) {
    int item = t + it * 128;        // 0..4095
    int jc = item & 255;
    int rr = item >> 8;             // 0..15
    int b  = b0 + rr;
    float wsum = bw[jc], bsum = bb[jc];
    #pragma unroll
    for (int k = 0; k < KSPLIT; ++k) {
      wsum += partials[((uint64_t)(0 * KSPLIT + k) * NROWS + b) * ACCH + jc];
      bsum += partials[((uint64_t)(1 * KSPLIT + k) * NROWS + b) * ACCH + jc];
    }
    float s = stm[b];
    float lo = (1.f - s) * wsum + s * bsum;
    float hi = (1.f - s) * bsum + s * wsum;
    in1[rr * 513 + jc]       = fminf(fmaxf(lo, 0.f), 1.f);
    in1[rr * 513 + 256 + jc] = fminf(fmaxf(hi, 0.f), 1.f);
  }
  __syncthreads();

  // layer 1: 512 -> 32, thread (row rl, o-group og) computes o = og*4+oi
  const int rl = t >> 3, og = t & 7;
  float a1[4] = {0.f, 0.f, 0.f, 0.f};
  for (int j = 0; j < 512; j += 4) {
    float v0 = in1[rl * 513 + j];
    float v1 = in1[rl * 513 + j + 1];
    float v2 = in1[rl * 513 + j + 2];
    float v3 = in1[rl * 513 + j + 3];
    #pragma unroll
    for (int oi = 0; oi < 4; ++oi) {
      const float4 wv = *(const float4*)(w1 + (og * 4 + oi) * 512 + j);
      a1[oi] += v0 * wv.x + v1 * wv.y + v2 * wv.z + v3 * wv.w;
    }
  }
  #pragma unroll
  for (int oi = 0; oi < 4; ++oi) {
    int o = og * 4 + oi;
    out1c[rl * 33 + o] = fminf(fmaxf(a1[oi] + b1[o], 0.f), 1.f);
  }
  __syncthreads();

  // layer 2: 32 -> 32
  float a2[4] = {0.f, 0.f, 0.f, 0.f};
  for (int j = 0; j < 32; ++j) {
    float v = out1c[rl * 33 + j];
    #pragma unroll
    for (int oi = 0; oi < 4; ++oi) a2[oi] += v * w2[(og * 4 + oi) * 32 + j];
  }
  // layer 3: 32 -> 1 (clip then dot w_out), reduce across the 8 og lanes
  float p = 0.f;
  #pragma unroll
  for (int oi = 0; oi < 4; ++oi) {
    int o = og * 4 + oi;
    p += fminf(fmaxf(a2[oi] + b2[o], 0.f), 1.f) * w_out[o];
  }
  p += __shfl_xor(p, 1, 64);
  p += __shfl_xor(p, 2, 64);
  p += __shfl_xor(p, 4, 64);
  if (og == 0) out[b0 + rl] = p + b_out[0];
}

extern "C" void kernel_launch(void* const* d_in, const int* in_sizes, int n_in,
                              void* d_out, int out_size, void* d_ws, size_t ws_size,
                              hipStream_t stream) {
  (void)in_sizes; (void)n_in; (void)out_size; (void)ws_size;
  const float* wfeat   = (const float*)d_in[0];
  const float* bfeat   = (const float*)d_in[1];
  const float* stm     = (const float*)d_in[2];
  const float* w_white = (const float*)d_in[3];
  const float* b_white = (const float*)d_in[4];
  const float* w_black = (const float*)d_in[5];
  const float* b_black = (const float*)d_in[6];
  const float* w1      = (const float*)d_in[7];
  const float* b1      = (const float*)d_in[8];
  const float* w2      = (const float*)d_in[9];
  const float* b2      = (const float*)d_in[10];
  const float* w_out   = (const float*)d_in[11];
  const float* b_out   = (const float*)d_in[12];
  float* out = (float*)d_out;

  uint16_t* wf16     = (uint16_t*)d_ws;                                   // 41,943,040 B
  float*    partials = (float*)((char*)d_ws + (uint64_t)2 * ACCH * K_DIM * 2); // 67,108,864 B

  // kernel 1: weights fp32 -> fp16 (2*256*40960 / 8 per thread = 2,621,440 threads)
  convert_w_kernel<<<10240, 256, 0, stream>>>(w_white, w_black, wf16);

  // kernel 2: main GEMM, 160 KiB dynamic LDS (2x32K A-dbuf + 3x32K B-tribuf)
  (void)hipFuncSetAttribute((const void*)ft_gemm,
                            hipFuncAttributeMaxDynamicSharedMemorySize, 163840);
  ft_gemm<<<256, 512, 163840, stream>>>(wfeat, bfeat, wf16, partials);

  // kernel 3: fused reduce + mix + clip + MLP
  tail_kernel<<<512, 128, 0, stream>>>(partials, stm, b_white, b_black,
                                       w1, b1, w2, b2, w_out, b_out, out);
}